// Round 8
// baseline (18273.564 us; speedup 1.0000x reference)
//
#include <hip/hip_runtime.h>
#include <stdint.h>

// ---------------- constants ----------------
#define NWG   128        // cooperative grid: 1 WG per CU
#define NTHR  256
#define Tsz   512
#define TC    16         // steps per chunk; zx chunk buffer = TC*8KB = 128KB/WG (= dead wc0 slice)
#define NC    (Tsz / TC)

typedef __attribute__((ext_vector_type(8))) short short8;      // 8 bf16 (4 VGPRs)
typedef __attribute__((ext_vector_type(4))) float f32x4;
typedef __attribute__((ext_vector_type(4))) unsigned uintx4;   // asm-legal 128b vector

__device__ __forceinline__ unsigned short f2bf(float f) {
    unsigned u = __builtin_bit_cast(unsigned, f);
    u += 0x7fffu + ((u >> 16) & 1u);          // RNE
    return (unsigned short)(u >> 16);
}
__device__ __forceinline__ float sigm(float x) {
    float e = __expf(-__builtin_fabsf(x));
    float r = 1.0f / (1.0f + e);
    return x >= 0.0f ? r : 1.0f - r;          // overflow-safe
}
__device__ __forceinline__ float tanh_(float x) {
    float e = __expf(-2.0f * __builtin_fabsf(x));
    float r = (1.0f - e) / (1.0f + e);
    return x >= 0.0f ? r : -r;                // overflow-safe
}

// ---- device-coherent asm primitives (round-3 lesson: waitcnt INSIDE asm
// for loads; stores are hazard-free).  sc0 sc1 = write through to LLC. ----
__device__ __forceinline__ void st16_cc(unsigned short* p, uintx4 v) {
    asm volatile("global_store_dwordx4 %0, %1, off sc0 sc1" :: "v"(p), "v"(v) : "memory");
}
__device__ __forceinline__ void st4_cc(unsigned* p, unsigned v) {
    asm volatile("global_store_dword %0, %1, off sc0 sc1" :: "v"(p), "v"(v) : "memory");
}
__device__ __forceinline__ void drain_vm() {
    asm volatile("s_waitcnt vmcnt(0)" ::: "memory");
}
__device__ __forceinline__ unsigned ld4_cc(const unsigned* p) {
    unsigned v;
    asm volatile("global_load_dword %0, %1, off sc0 sc1\n\t"
                 "s_waitcnt vmcnt(0)"
                 : "=&v"(v) : "v"(p) : "memory");
    return v;
}

// ---------------- prep kernels ----------------
// x [B][T][D] f32  ->  xb [t][kb(128)][b(64)][8] bf16   (MFMA A-fragment-native)
__global__ void cast_x(const float* __restrict__ x, unsigned short* __restrict__ xb) {
    int o = blockIdx.x * 256 + threadIdx.x;       // 512*128*64 = 4,194,304
    int t = o >> 13;
    int r = o & 8191;
    int kb = r >> 6;
    int b  = r & 63;
    const float* s = x + (((size_t)b * Tsz + t) * 1024 + kb * 8);
    float4 f0 = ((const float4*)s)[0];
    float4 f1 = ((const float4*)s)[1];
    unsigned short tmp[8];
    tmp[0] = f2bf(f0.x); tmp[1] = f2bf(f0.y); tmp[2] = f2bf(f0.z); tmp[3] = f2bf(f0.w);
    tmp[4] = f2bf(f1.x); tmp[5] = f2bf(f1.y); tmp[6] = f2bf(f1.z); tmp[7] = f2bf(f1.w);
    ((uint4*)xb)[o] = *(const uint4*)tmp;
}

// W [2048][4096] f32 -> wc [w(128)][kb(256)][n(32)][8] bf16 in MFMA B-layout, columns permuted
__global__ void build_wc(const float* __restrict__ W0, const float* __restrict__ W1,
                         unsigned short* __restrict__ wc0, unsigned short* __restrict__ wc1) {
    int o = blockIdx.x * 256 + threadIdx.x;       // 2*128*256*32 = 2,097,152
    int layer = o >> 20;
    int r = o & 1048575;
    int w  = r >> 13;
    int r2 = r & 8191;
    int kb = r2 >> 5;
    int n  = r2 & 31;
    int nt = n >> 4, n16 = n & 15;
    int g = n16 >> 2, q = n16 & 3;
    int col = g * 1024 + w * 8 + nt * 4 + q;
    const float* W = layer ? W1 : W0;
    unsigned short* wc = layer ? wc1 : wc0;
    unsigned short tmp[8];
#pragma unroll
    for (int i = 0; i < 8; ++i) tmp[i] = f2bf(W[(size_t)(kb * 8 + i) * 4096 + col]);
    ((uint4*)wc)[r] = *(const uint4*)tmp;
}

// permuted biases pb[layer][w][32] f32 + flag-barrier slots (ws poisoned each launch!)
__global__ void build_pb(const float* __restrict__ b0, const float* __restrict__ b1,
                         float* __restrict__ pb, unsigned* __restrict__ flg) {
    int o = blockIdx.x * 256 + threadIdx.x;       // 8192
    if (o < 2048) flg[o] = 0u;                    // 128 slots x 64B stride
    int layer = o >> 12;
    int r = o & 4095;
    int w = r >> 5;
    int n = r & 31;
    int nt = n >> 4, n16 = n & 15;
    int g = n16 >> 2, q = n16 & 3;
    const float* bb = layer ? b1 : b0;
    pb[o] = bb[g * 1024 + w * 8 + nt * 4 + q];
}

// ---------------- flat all-to-all flag barrier ----------------
// Each WG stores a monotonic seq to its OWN 64B slot; 128 threads each poll
// one slot.  No cache maintenance -> L2 stays hot.  Contract: bypass ring
// stores drained BEFORE the flag store; ring reads issued AFTER exit.
__device__ __forceinline__ void gbar(unsigned* flg, unsigned& bseq, int w, int tid) {
    ++bseq;
    __syncthreads();
    if (tid == 0) st4_cc(flg + w * 16, bseq);
    if (tid < 128) {
        while (ld4_cc(flg + tid * 16) < bseq) __builtin_amdgcn_s_sleep(1);
    }
    __syncthreads();
}
// Full-fence variant (L2 writeback + invalidate): ONLY at init and the
// layer 0 -> 1 boundary (publishes cached y0b, clears layer-0 ring lines).
__device__ __forceinline__ void gbar_full(unsigned* flg, unsigned& bseq, int w, int tid) {
    ++bseq;
    __syncthreads();
    if (tid == 0) { __threadfence(); st4_cc(flg + w * 16, bseq); }   // release: wb L2
    if (tid < 128) {
        while (ld4_cc(flg + tid * 16) < bseq) __builtin_amdgcn_s_sleep(1);
    }
    __syncthreads();
    if (tid == 0) __threadfence();                // acquire: inv L1/L2
    __syncthreads();
}

// ---------------- K=512 GEMM slice: z[32x32] += A[32rows x 512] * Wlds[512 x 32] ----
// ALL 32 A-loads hoisted up front (128 VGPR; launch_bounds(256,1) allows up
// to 512): ONE memory latency per call instead of 8 (round-5's depth-1 paid
// ~a full latency per group).  B from LDS (off the vmcnt chain).  Compiler
// inserts counted vmcnt/lgkmcnt before each dependent MFMA (m97-style).
__device__ __forceinline__ void gemm512(const unsigned short* a0p,
                                        const short8* lb,
                                        f32x4& c00, f32x4& c01, f32x4& c10, f32x4& c11) {
    short8 A0[16], A1[16];
#pragma unroll
    for (int s = 0; s < 16; ++s) {
        A0[s] = *(const short8*)(a0p + s * 2048);          // kb += 4 per s
        A1[s] = *(const short8*)(a0p + s * 2048 + 128);    // +16 rows
    }
#pragma unroll
    for (int s = 0; s < 16; ++s) {
        short8 bf0 = lb[s * 128];        // kb += 4 per s -> +128 16B units
        short8 bf1 = lb[s * 128 + 16];   // +16 cols
        c00 = __builtin_amdgcn_mfma_f32_16x16x32_bf16(A0[s], bf0, c00, 0, 0, 0);
        c01 = __builtin_amdgcn_mfma_f32_16x16x32_bf16(A0[s], bf1, c01, 0, 0, 0);
        c10 = __builtin_amdgcn_mfma_f32_16x16x32_bf16(A1[s], bf0, c10, 0, 0, 0);
        c11 = __builtin_amdgcn_mfma_f32_16x16x32_bf16(A1[s], bf1, c11, 0, 0, 0);
    }
}

// ---------------- persistent LSTM loop ----------------
// Per layer, per 16-step chunk:
//   PHASE A (parallel): zx[tt] = x_t . Wx (K=1024 over kh waves) -- no
//     sequential dependence.  zx is WG-PRIVATE and lives in the WG's OWN
//     dead wc0 slice (wc0 read once at layer-0 staging, same WG, program-
//     ordered before the overwrite; slices are disjoint across WGs; wc1
//     untouched).  Total ws footprint == round-5's proven 235,577,344 B.
//   PHASE B (serial): h-GEMM (K=1024, 4-wave split) + gates + ring publish
//     + flag barrier.  No phase barrier needed: per-step gbar bounds skew,
//     and chunk c+1's PHASE A touches only private/stable data.
// hring: 513 write-once slots (sc0sc1-written, cache-read; no stale lines).
__launch_bounds__(NTHR, 1)
__global__ void lstm_loop(const unsigned short* __restrict__ xb,
                          unsigned short* __restrict__ y0b,
                          const unsigned short* wc0,      // no restrict: aliases zx
                          const unsigned short* __restrict__ wc1,
                          const float* __restrict__ pb,
                          const int* __restrict__ lens,
                          unsigned short* __restrict__ hring,
                          float* __restrict__ cst,
                          unsigned* __restrict__ flg,
                          float* zx,                      // no restrict: aliases wc0
                          float* __restrict__ out) {
    extern __shared__ short8 lwc[];     // 131072 B: weight slice [kb 0..255][n 32] 16B units
    __shared__ float zbuf[2][64][33];   // [kh][b][col32], +1 pad vs bank conflicts
    __shared__ float pbl[2][32];
    __shared__ __align__(16) unsigned short hsh[64][8];   // h staging -> 64 dwordx4 stores

    const int w = blockIdx.x;
    const int tid = threadIdx.x;
    const int lane = tid & 63;
    const int wave = tid >> 6;
    const int m  = wave & 1;     // M-pair: rows [m*32, m*32+32)
    const int kh = wave >> 1;    // K-half within the 1024-wide operand
    const int q16 = lane >> 4;
    const int n16 = lane & 15;

    // per-wave A/B fragment offsets (element units of 8 = 16B)
    const int aoff = ((kh * 64 + q16) * 64 + m * 32 + n16) * 8;   // [kb][b][8]
    const short8* lbx = lwc + (kh * 64 + q16) * 32 + n16;         // x-part: kb 0..127
    const short8* lbh = lbx + 128 * 32;                           // h-part: kb 128..255
    float* zxw = zx + (size_t)w * (TC * 2048);                    // this WG's chunk buffer

    // ---- per-launch init (ws is re-poisoned every launch) ----
    st4_cc((unsigned*)hring + w * 256 + tid, 0u);             // zero ring slot 0 (bypass)
    {
        int ly = tid >> 7, r = tid & 127;                     // zero c rows [8w,8w+8), both layers
        ((float4*)(cst + ly * 65536 + w * 512))[r] = make_float4(0.f, 0.f, 0.f, 0.f);
    }
    if (tid < 64) pbl[tid >> 5][tid & 31] = pb[((tid >> 5) * 128 + w) * 32 + (tid & 31)];
    const int lenb = lens[tid & 63];
    drain_vm();                                               // slot-0 zeros at LLC
    unsigned bseq = 0;
    gbar_full(flg, bseq, w, tid);

    for (int layer = 0; layer < 2; ++layer) {
        const unsigned short* xsrc = layer ? y0b : xb;
        const unsigned short* wc   = layer ? wc1 : wc0;

        // ---- stage this layer's 128 KB weight slice into LDS (once).
        //      (layer 0: this READ of the wc0 slice precedes, in program
        //       order of the SAME WG, any zx overwrite of it.) ----
        {
            const short8* gsrc = (const short8*)(wc + (size_t)w * 65536);
#pragma unroll 4
            for (int i = 0; i < 32; ++i) lwc[tid + i * 256] = gsrc[tid + i * 256];
        }
        __syncthreads();

        float hpf[2] = {0.f, 0.f};   // this thread's own h(b,jj)/h(b,jj+4): hold-state source

        for (int c = 0; c < NC; ++c) {
            const int tbase = c * TC;

            // ======== PHASE A: zx[tt] = x_t . Wx  (parallel, WG-private out) ========
            for (int tt = 0; tt < TC; ++tt) {
                const int t = tbase + tt;
                f32x4 c00 = {0.f,0.f,0.f,0.f}, c01 = {0.f,0.f,0.f,0.f};
                f32x4 c10 = {0.f,0.f,0.f,0.f}, c11 = {0.f,0.f,0.f,0.f};
                gemm512(xsrc + (size_t)t * 65536 + aoff, lbx, c00, c01, c10, c11);
                {
                    const int rowb = m * 32 + q16 * 4;
#pragma unroll
                    for (int r = 0; r < 4; ++r) {
                        zbuf[kh][rowb + r][n16]           = c00[r];
                        zbuf[kh][rowb + r][n16 + 16]      = c01[r];
                        zbuf[kh][rowb + 16 + r][n16]      = c10[r];
                        zbuf[kh][rowb + 16 + r][n16 + 16] = c11[r];
                    }
                }
                __syncthreads();
                {   // combine kh halves, write 8 contiguous f32 per thread (coalesced)
                    float* zxp = zxw + tt * 2048;
                    const int bb = tid >> 2, c0 = (tid & 3) * 8;
                    float4 v0, v1;
                    v0.x = zbuf[0][bb][c0+0] + zbuf[1][bb][c0+0];
                    v0.y = zbuf[0][bb][c0+1] + zbuf[1][bb][c0+1];
                    v0.z = zbuf[0][bb][c0+2] + zbuf[1][bb][c0+2];
                    v0.w = zbuf[0][bb][c0+3] + zbuf[1][bb][c0+3];
                    v1.x = zbuf[0][bb][c0+4] + zbuf[1][bb][c0+4];
                    v1.y = zbuf[0][bb][c0+5] + zbuf[1][bb][c0+5];
                    v1.z = zbuf[0][bb][c0+6] + zbuf[1][bb][c0+6];
                    v1.w = zbuf[0][bb][c0+7] + zbuf[1][bb][c0+7];
                    ((float4*)(zxp + bb * 32 + c0))[0] = v0;
                    ((float4*)(zxp + bb * 32 + c0))[1] = v1;
                }
                __syncthreads();
            }

            // ======== PHASE B: recurrent steps of this chunk ========
            for (int tt = 0; tt < TC; ++tt) {
                const int t = tbase + tt;
                // zx gate values: 8 scalar f32 (own-L1/L2 hot) -- issued before
                // the GEMM so their latency hides under it.
                const float* zxp = zxw + tt * 2048 + (tid & 63) * 32;
                float zg[8];
#pragma unroll
                for (int k = 0; k < 4; ++k) {
                    zg[k]     = zxp[wave + k * 4];        // h2=0: cb = wave
                    zg[4 + k] = zxp[16 + wave + k * 4];   // h2=1: cb = 16+wave
                }

                f32x4 c00 = {0.f,0.f,0.f,0.f}, c01 = {0.f,0.f,0.f,0.f};
                f32x4 c10 = {0.f,0.f,0.f,0.f}, c11 = {0.f,0.f,0.f,0.f};
                gemm512(hring + (size_t)t * 65536 + aoff, lbh, c00, c01, c10, c11);
                {
                    const int rowb = m * 32 + q16 * 4;
#pragma unroll
                    for (int r = 0; r < 4; ++r) {
                        zbuf[kh][rowb + r][n16]           = c00[r];
                        zbuf[kh][rowb + r][n16 + 16]      = c01[r];
                        zbuf[kh][rowb + 16 + r][n16]      = c10[r];
                        zbuf[kh][rowb + 16 + r][n16 + 16] = c11[r];
                    }
                }
                __syncthreads();

                // ---- gates + state update (this WG owns j = 8w..8w+7) ----
                const int b = tid & 63;
                const bool active = (t < lenb);
#pragma unroll
                for (int h2 = 0; h2 < 2; ++h2) {
                    const int jj = wave + h2 * 4;
                    const int cb = h2 * 16 + wave;
                    float zi = zg[h2*4+0] + zbuf[0][b][cb]      + zbuf[1][b][cb]      + pbl[layer][cb];
                    float zc = zg[h2*4+1] + zbuf[0][b][cb + 4]  + zbuf[1][b][cb + 4]  + pbl[layer][cb + 4];
                    float zf = zg[h2*4+2] + zbuf[0][b][cb + 8]  + zbuf[1][b][cb + 8]  + pbl[layer][cb + 8];
                    float zo = zg[h2*4+3] + zbuf[0][b][cb + 12] + zbuf[1][b][cb + 12] + pbl[layer][cb + 12];
                    if (active) {
                        const int ci = (layer * 1024 + w * 8 + jj) * 64 + b;
                        float cc = cst[ci];
                        float cn = cc * sigm(zf + 1.0f) + sigm(zi) * tanh_(zc);
                        cst[ci] = cn;
                        hpf[h2] = tanh_(cn) * sigm(zo);
                    }  // inactive: hold hpf (dynamic_rnn state-hold)
                    unsigned short hv = f2bf(hpf[h2]);
                    hsh[b][jj] = hv;
                    const int hi = (w * 64 + b) * 8 + jj;
                    if (layer == 0) {
                        y0b[(size_t)t * 65536 + hi] = active ? hv : (unsigned short)0;
                    } else {
                        out[(size_t)(b * Tsz + t) * 1024 + w * 8 + jj] = active ? hpf[h2] : 0.0f;
                    }
                }
                __syncthreads();   // hsh complete
                if (tid < 64) {    // wave 0: publish h slice to ring slot t+1 (bypass)
                    uintx4 v = ((const uintx4*)hsh)[tid];
                    st16_cc((unsigned short*)hring + (size_t)(t + 1) * 65536
                            + (size_t)w * 512 + (size_t)tid * 8, v);
                    drain_vm();    // h at LLC before the flag store (thread 0 here)
                }
                gbar(flg, bseq, w, tid);
            }
        }

        // ---- final (h, c) stacks: straight from registers / private cst ----
        {
            const int b = tid & 63;
#pragma unroll
            for (int h2 = 0; h2 < 2; ++h2) {
                const int jj = wave + h2 * 4;
                const int j = w * 8 + jj;
                out[33554432 + layer * 65536 + b * 1024 + j]          = hpf[h2];                          // h_stack
                out[33554432 + 131072 + layer * 65536 + b * 1024 + j] = cst[(layer * 1024 + j) * 64 + b]; // c_stack
            }
        }
        if (layer == 0) {
            // re-zero ring slot 0 for layer 1 (bypass, drained); full-fence barrier
            // publishes cached y0b AND invalidates layer-0 ring/zx cached lines.
            st4_cc((unsigned*)hring + w * 256 + tid, 0u);
            drain_vm();
            gbar_full(flg, bseq, w, tid);
        }
    }
}

// ---------------- launcher ----------------
extern "C" void kernel_launch(void* const* d_in, const int* in_sizes, int n_in,
                              void* d_out, int out_size, void* d_ws, size_t ws_size,
                              hipStream_t stream) {
    const float* x    = (const float*)d_in[0];
    const int*   lens = (const int*)d_in[1];     // integer inputs arrive as int32
    const float* W0   = (const float*)d_in[2];
    const float* b0   = (const float*)d_in[3];
    const float* W1   = (const float*)d_in[4];
    const float* b1   = (const float*)d_in[5];
    char* ws = (char*)d_ws;

    unsigned short* xb   = (unsigned short*)(ws);                    //  67,108,864 B
    unsigned short* y0b  = (unsigned short*)(ws + 67108864);         //  67,108,864 B
    unsigned short* wc0  = (unsigned short*)(ws + 134217728);        //  16,777,216 B (reused as zx!)
    unsigned short* wc1  = (unsigned short*)(ws + 150994944);        //  16,777,216 B
    float*          pb   = (float*)         (ws + 167772160);        //      32,768 B
    float*          cst  = (float*)         (ws + 167804928);        //     524,288 B
    unsigned*       flg  = (unsigned*)      (ws + 168329216);        //       8,192 B
    unsigned short* hrng = (unsigned short*)(ws + 168337408);        //  67,239,936 B (513 slots)
    float*          zx   = (float*)         (ws + 134217728);        //  = wc0 (dead after staging)
                                                                     //  total 235,577,344 B (== round 5)

    hipLaunchKernelGGL(cast_x,   dim3(16384), dim3(256), 0, stream, x, xb);
    hipLaunchKernelGGL(build_wc, dim3(8192),  dim3(256), 0, stream, W0, W1, wc0, wc1);
    hipLaunchKernelGGL(build_pb, dim3(32),    dim3(256), 0, stream, b0, b1, pb, flg);

    float* out = (float*)d_out;
    void* args[] = { &xb, &y0b, &wc0, &wc1, &pb, &lens, &hrng, &cst, &flg, &zx, &out };
    (void)hipLaunchCooperativeKernel((void*)lstm_loop, dim3(NWG), dim3(NTHR), args,
                                     131072 /* dynamic LDS: weight slice */, stream);
}

// Round 9
// 7670.496 us; speedup vs baseline: 2.3823x; 2.3823x over previous
//
#include <hip/hip_runtime.h>
#include <stdint.h>

// ---------------- constants ----------------
#define NWG   128        // cooperative grid: 1 WG per CU
#define NTHR  512        // 8 waves: (op x,h) x (m row-half) x (khalf K-half)
#define Tsz   512

typedef __attribute__((ext_vector_type(8))) short short8;      // 8 bf16 (4 VGPRs)
typedef __attribute__((ext_vector_type(4))) float f32x4;
typedef __attribute__((ext_vector_type(4))) unsigned uintx4;   // asm-legal 128b vector

__device__ __forceinline__ unsigned short f2bf(float f) {
    unsigned u = __builtin_bit_cast(unsigned, f);
    u += 0x7fffu + ((u >> 16) & 1u);          // RNE
    return (unsigned short)(u >> 16);
}
__device__ __forceinline__ float sigm(float x) {
    float e = __expf(-__builtin_fabsf(x));
    float r = 1.0f / (1.0f + e);
    return x >= 0.0f ? r : 1.0f - r;          // overflow-safe
}
__device__ __forceinline__ float tanh_(float x) {
    float e = __expf(-2.0f * __builtin_fabsf(x));
    float r = (1.0f - e) / (1.0f + e);
    return x >= 0.0f ? r : -r;                // overflow-safe
}

// ---- device-coherent asm primitives (round-3 lesson: waitcnt INSIDE asm
// for loads; stores are hazard-free).  sc0 sc1 = write through to LLC. ----
__device__ __forceinline__ void st16_cc(unsigned short* p, uintx4 v) {
    asm volatile("global_store_dwordx4 %0, %1, off sc0 sc1" :: "v"(p), "v"(v) : "memory");
}
__device__ __forceinline__ void st4_cc(unsigned* p, unsigned v) {
    asm volatile("global_store_dword %0, %1, off sc0 sc1" :: "v"(p), "v"(v) : "memory");
}
__device__ __forceinline__ void drain_vm() {
    asm volatile("s_waitcnt vmcnt(0)" ::: "memory");
}
__device__ __forceinline__ unsigned ld4_cc(const unsigned* p) {
    unsigned v;
    asm volatile("global_load_dword %0, %1, off sc0 sc1\n\t"
                 "s_waitcnt vmcnt(0)"
                 : "=&v"(v) : "v"(p) : "memory");
    return v;
}

// ---------------- prep kernels ----------------
// x [B][T][D] f32  ->  xb [t][kb(128)][b(64)][8] bf16   (MFMA A-fragment-native)
__global__ void cast_x(const float* __restrict__ x, unsigned short* __restrict__ xb) {
    int o = blockIdx.x * 256 + threadIdx.x;       // 512*128*64 = 4,194,304
    int t = o >> 13;
    int r = o & 8191;
    int kb = r >> 6;
    int b  = r & 63;
    const float* s = x + (((size_t)b * Tsz + t) * 1024 + kb * 8);
    float4 f0 = ((const float4*)s)[0];
    float4 f1 = ((const float4*)s)[1];
    unsigned short tmp[8];
    tmp[0] = f2bf(f0.x); tmp[1] = f2bf(f0.y); tmp[2] = f2bf(f0.z); tmp[3] = f2bf(f0.w);
    tmp[4] = f2bf(f1.x); tmp[5] = f2bf(f1.y); tmp[6] = f2bf(f1.z); tmp[7] = f2bf(f1.w);
    ((uint4*)xb)[o] = *(const uint4*)tmp;
}

// W [2048][4096] f32 -> wc [w(128)][kb(256)][n(32)][8] bf16 in MFMA B-layout, columns permuted
__global__ void build_wc(const float* __restrict__ W0, const float* __restrict__ W1,
                         unsigned short* __restrict__ wc0, unsigned short* __restrict__ wc1) {
    int o = blockIdx.x * 256 + threadIdx.x;       // 2*128*256*32 = 2,097,152
    int layer = o >> 20;
    int r = o & 1048575;
    int w  = r >> 13;
    int r2 = r & 8191;
    int kb = r2 >> 5;
    int n  = r2 & 31;
    int nt = n >> 4, n16 = n & 15;
    int g = n16 >> 2, q = n16 & 3;
    int col = g * 1024 + w * 8 + nt * 4 + q;
    const float* W = layer ? W1 : W0;
    unsigned short* wc = layer ? wc1 : wc0;
    unsigned short tmp[8];
#pragma unroll
    for (int i = 0; i < 8; ++i) tmp[i] = f2bf(W[(size_t)(kb * 8 + i) * 4096 + col]);
    ((uint4*)wc)[r] = *(const uint4*)tmp;
}

// permuted biases pb[layer][w][32] f32 + flag-barrier slots (ws poisoned each launch!)
__global__ void build_pb(const float* __restrict__ b0, const float* __restrict__ b1,
                         float* __restrict__ pb, unsigned* __restrict__ flg) {
    int o = blockIdx.x * 256 + threadIdx.x;       // 8192
    if (o < 2048) flg[o] = 0u;                    // 128 slots x 64B stride
    int layer = o >> 12;
    int r = o & 4095;
    int w = r >> 5;
    int n = r & 31;
    int nt = n >> 4, n16 = n & 15;
    int g = n16 >> 2, q = n16 & 3;
    const float* bb = layer ? b1 : b0;
    pb[o] = bb[g * 1024 + w * 8 + nt * 4 + q];
}

// ---------------- flat all-to-all flag barrier ----------------
// Each WG stores a monotonic seq to its OWN 64B slot; threads 0..127 each
// poll one slot.  No cache maintenance -> L2 stays hot.  Contract: bypass
// ring stores drained BEFORE the flag store; ring reads issued AFTER exit.
__device__ __forceinline__ void gbar(unsigned* flg, unsigned& bseq, int w, int tid) {
    ++bseq;
    __syncthreads();
    if (tid == 0) st4_cc(flg + w * 16, bseq);
    if (tid < 128) {
        while (ld4_cc(flg + tid * 16) < bseq) __builtin_amdgcn_s_sleep(1);
    }
    __syncthreads();
}
// Full-fence variant (L2 writeback + invalidate): ONLY at init and the
// layer 0 -> 1 boundary (publishes cached y0b, clears layer-0 ring lines).
__device__ __forceinline__ void gbar_full(unsigned* flg, unsigned& bseq, int w, int tid) {
    ++bseq;
    __syncthreads();
    if (tid == 0) { __threadfence(); st4_cc(flg + w * 16, bseq); }   // release: wb L2
    if (tid < 128) {
        while (ld4_cc(flg + tid * 16) < bseq) __builtin_amdgcn_s_sleep(1);
    }
    __syncthreads();
    if (tid == 0) __threadfence();                // acquire: inv L1/L2
    __syncthreads();
}

// ---------------- K=512 GEMM slice: z[32rows x 32cols] += A[32 x 512] * Wlds[512 x 32] ----
// ALL 32 A-loads hoisted (128 VGPR) -> ONE memory-latency exposure per step
// (round 5's depth-1 groups paid ~8).  B from LDS, off the vmcnt chain.
// Compiler inserts counted vmcnt/lgkmcnt before each dependent MFMA.
__device__ __forceinline__ void gemm512(const unsigned short* a0p,
                                        const short8* lb,
                                        f32x4& c00, f32x4& c01, f32x4& c10, f32x4& c11) {
    short8 A0[16], A1[16];
#pragma unroll
    for (int s = 0; s < 16; ++s) {
        A0[s] = *(const short8*)(a0p + s * 2048);          // kb += 4 per s
        A1[s] = *(const short8*)(a0p + s * 2048 + 128);    // +16 rows
    }
#pragma unroll
    for (int s = 0; s < 16; ++s) {
        short8 bf0 = lb[s * 128];        // kb += 4 per s -> +128 16B units
        short8 bf1 = lb[s * 128 + 16];   // +16 cols
        c00 = __builtin_amdgcn_mfma_f32_16x16x32_bf16(A0[s], bf0, c00, 0, 0, 0);
        c01 = __builtin_amdgcn_mfma_f32_16x16x32_bf16(A0[s], bf1, c01, 0, 0, 0);
        c10 = __builtin_amdgcn_mfma_f32_16x16x32_bf16(A1[s], bf0, c10, 0, 0, 0);
        c11 = __builtin_amdgcn_mfma_f32_16x16x32_bf16(A1[s], bf1, c11, 0, 0, 0);
    }
}

// ---------------- persistent LSTM loop ----------------
// ROUND-9 STRUCTURE (revert of round-8 phase split, which serialized the
// x-GEMM and bounced zx through HBM: 18.3ms vs round-5 11.5ms):
//   8 waves, wave = (op, khalf, m) = (w>>2, (w>>1)&1, w&1).
//   x-waves (op=0) and h-waves (op=1) run CONCURRENTLY each step (round-5
//   wave parallelism), but each wave now covers only K=512 -> its 32 A-loads
//   are FULLY hoisted -> one latency exposure instead of round-5's 8.
//   K-half reduction: x-k0 writes zbuf[0]; x-k1 RMWs zbuf[0] after a sync
//   (saves one 8.4KB slice to fit 160KB LDS); h-k0 -> zbuf[1], h-k1 -> zbuf[2].
//   Gates sum the 3 slices + bias.
// hring: 513 write-once slots (sc0sc1-written, cache-read; no stale lines).
__launch_bounds__(NTHR, 2)
__global__ void lstm_loop(const unsigned short* __restrict__ xb,
                          unsigned short* __restrict__ y0b,
                          const unsigned short* __restrict__ wc0,
                          const unsigned short* __restrict__ wc1,
                          const float* __restrict__ pb,
                          const int* __restrict__ lens,
                          unsigned short* __restrict__ hring,
                          float* __restrict__ cst,
                          unsigned* __restrict__ flg,
                          float* __restrict__ out) {
    extern __shared__ short8 lwc[];     // 131072 B: weight slice [kb 0..255][n 32] 16B units
    __shared__ float zbuf[3][64][33];   // [slice][b][col32], +1 pad vs bank conflicts (25.3 KB)
    __shared__ float pbl[2][32];
    __shared__ __align__(16) unsigned short hsh[64][8];   // h staging -> 64 dwordx4 stores

    const int w = blockIdx.x;
    const int tid = threadIdx.x;
    const int lane = tid & 63;
    const int wave = tid >> 6;        // 0..7
    const int m     = wave & 1;        // row half: rows [m*32, m*32+32)
    const int khalf = (wave >> 1) & 1; // K half within the operand's K=1024
    const int op    = wave >> 2;       // 0 = x operand, 1 = h operand
    const int q16 = lane >> 4;
    const int n16 = lane & 15;

    // per-wave A offset (ushort units) and B base in LDS (short8 units)
    const int aoff = ((khalf * 64 + q16) * 64 + m * 32 + n16) * 8;       // [kb][b][8]
    const short8* lb = lwc + ((op * 128 + khalf * 64 + q16) * 32 + n16); // kb base in lwc

    // ---- per-launch init (ws is re-poisoned every launch) ----
    if (tid < 256) {
        st4_cc((unsigned*)hring + w * 256 + tid, 0u);         // zero ring slot 0 (bypass)
        int ly = tid >> 7, r = tid & 127;                     // zero c rows [8w,8w+8), both layers
        ((float4*)(cst + ly * 65536 + w * 512))[r] = make_float4(0.f, 0.f, 0.f, 0.f);
    }
    if (tid < 64) pbl[tid >> 5][tid & 31] = pb[((tid >> 5) * 128 + w) * 32 + (tid & 31)];
    const int lenb = lens[tid & 63];
    drain_vm();                                               // slot-0 zeros at LLC
    unsigned bseq = 0;
    gbar_full(flg, bseq, w, tid);

    for (int layer = 0; layer < 2; ++layer) {
        const unsigned short* xsrc = layer ? y0b : xb;
        const unsigned short* wc   = layer ? wc1 : wc0;

        // ---- stage this layer's 128 KB weight slice into LDS (once) ----
        {
            const short8* gsrc = (const short8*)(wc + (size_t)w * 65536);
#pragma unroll 4
            for (int i = 0; i < 16; ++i) lwc[tid + i * 512] = gsrc[tid + i * 512];
        }
        __syncthreads();

        float hpf = 0.f;   // this thread's own h(b, jj): hold-state source
        const int b  = tid & 63;
        const int jj = wave;            // this thread's j within the WG's 8
        const int cb = (jj >> 2) * 16 + (jj & 3);

        for (int t = 0; t < Tsz; ++t) {
            // ---- GEMM: all 8 waves concurrently, one latency exposure each ----
            f32x4 c00 = {0.f,0.f,0.f,0.f}, c01 = {0.f,0.f,0.f,0.f};
            f32x4 c10 = {0.f,0.f,0.f,0.f}, c11 = {0.f,0.f,0.f,0.f};
            const unsigned short* Abase = op ? (hring + (size_t)t * 65536)
                                             : (xsrc  + (size_t)t * 65536);
            gemm512(Abase + aoff, lb, c00, c01, c10, c11);

            // ---- stage 1: direct zbuf writes (x-k0 -> 0, h-k0 -> 1, h-k1 -> 2) ----
            const int rowb = m * 32 + q16 * 4;
            if (!(op == 0 && khalf == 1)) {
                const int slice = op ? (1 + khalf) : 0;
#pragma unroll
                for (int r = 0; r < 4; ++r) {
                    zbuf[slice][rowb + r][n16]           = c00[r];
                    zbuf[slice][rowb + r][n16 + 16]      = c01[r];
                    zbuf[slice][rowb + 16 + r][n16]      = c10[r];
                    zbuf[slice][rowb + 16 + r][n16 + 16] = c11[r];
                }
            }
            __syncthreads();
            // ---- stage 2: x-k1 accumulates into slice 0 (disjoint rows per m) ----
            if (op == 0 && khalf == 1) {
#pragma unroll
                for (int r = 0; r < 4; ++r) {
                    zbuf[0][rowb + r][n16]           += c00[r];
                    zbuf[0][rowb + r][n16 + 16]      += c01[r];
                    zbuf[0][rowb + 16 + r][n16]      += c10[r];
                    zbuf[0][rowb + 16 + r][n16 + 16] += c11[r];
                }
            }
            __syncthreads();

            // ---- gates + state update: 512 threads, one (b, jj) each ----
            const bool active = (t < lenb);
            {
                float zi = zbuf[0][b][cb]      + zbuf[1][b][cb]      + zbuf[2][b][cb]      + pbl[layer][cb];
                float zc = zbuf[0][b][cb + 4]  + zbuf[1][b][cb + 4]  + zbuf[2][b][cb + 4]  + pbl[layer][cb + 4];
                float zf = zbuf[0][b][cb + 8]  + zbuf[1][b][cb + 8]  + zbuf[2][b][cb + 8]  + pbl[layer][cb + 8];
                float zo = zbuf[0][b][cb + 12] + zbuf[1][b][cb + 12] + zbuf[2][b][cb + 12] + pbl[layer][cb + 12];
                if (active) {
                    const int ci = (layer * 1024 + w * 8 + jj) * 64 + b;
                    float cc = cst[ci];
                    float cn = cc * sigm(zf + 1.0f) + sigm(zi) * tanh_(zc);
                    cst[ci] = cn;
                    hpf = tanh_(cn) * sigm(zo);
                }  // inactive: hold hpf (dynamic_rnn state-hold)
                unsigned short hv = f2bf(hpf);
                hsh[b][jj] = hv;
                const int hi = (w * 64 + b) * 8 + jj;
                if (layer == 0) {
                    y0b[(size_t)t * 65536 + hi] = active ? hv : (unsigned short)0;
                } else {
                    out[(size_t)(b * Tsz + t) * 1024 + w * 8 + jj] = active ? hpf : 0.0f;
                }
            }
            __syncthreads();   // hsh complete
            if (tid < 64) {    // wave 0: publish h slice to ring slot t+1 (bypass)
                uintx4 v = ((const uintx4*)hsh)[tid];
                st16_cc((unsigned short*)hring + (size_t)(t + 1) * 65536
                        + (size_t)w * 512 + (size_t)tid * 8, v);
                drain_vm();    // h at LLC before the flag store (thread 0 here)
            }
            gbar(flg, bseq, w, tid);
        }
        // ---- final (h, c) stacks: straight from registers / private cst ----
        {
            const int j = w * 8 + jj;
            out[33554432 + layer * 65536 + b * 1024 + j]          = hpf;                                  // h_stack
            out[33554432 + 131072 + layer * 65536 + b * 1024 + j] = cst[(layer * 1024 + j) * 64 + b];     // c_stack
        }
        if (layer == 0) {
            // re-zero ring slot 0 for layer 1 (bypass, drained); full-fence barrier
            // publishes cached y0b AND invalidates layer-0 ring cached lines.
            if (tid < 256) st4_cc((unsigned*)hring + w * 256 + tid, 0u);
            drain_vm();
            gbar_full(flg, bseq, w, tid);
        }
    }
}

// ---------------- launcher ----------------
extern "C" void kernel_launch(void* const* d_in, const int* in_sizes, int n_in,
                              void* d_out, int out_size, void* d_ws, size_t ws_size,
                              hipStream_t stream) {
    const float* x    = (const float*)d_in[0];
    const int*   lens = (const int*)d_in[1];     // integer inputs arrive as int32
    const float* W0   = (const float*)d_in[2];
    const float* b0   = (const float*)d_in[3];
    const float* W1   = (const float*)d_in[4];
    const float* b1   = (const float*)d_in[5];
    char* ws = (char*)d_ws;

    unsigned short* xb   = (unsigned short*)(ws);                    //  67,108,864 B
    unsigned short* y0b  = (unsigned short*)(ws + 67108864);         //  67,108,864 B
    unsigned short* wc0  = (unsigned short*)(ws + 134217728);        //  16,777,216 B
    unsigned short* wc1  = (unsigned short*)(ws + 150994944);        //  16,777,216 B
    float*          pb   = (float*)         (ws + 167772160);        //      32,768 B
    float*          cst  = (float*)         (ws + 167804928);        //     524,288 B
    unsigned*       flg  = (unsigned*)      (ws + 168329216);        //       8,192 B
    unsigned short* hrng = (unsigned short*)(ws + 168337408);        //  67,239,936 B (513 slots)
                                                                     //  total 235,577,344 B (proven)

    hipLaunchKernelGGL(cast_x,   dim3(16384), dim3(256), 0, stream, x, xb);
    hipLaunchKernelGGL(build_wc, dim3(8192),  dim3(256), 0, stream, W0, W1, wc0, wc1);
    hipLaunchKernelGGL(build_pb, dim3(32),    dim3(256), 0, stream, b0, b1, pb, flg);

    float* out = (float*)d_out;
    void* args[] = { &xb, &y0b, &wc0, &wc1, &pb, &lens, &hrng, &cst, &flg, &out };
    (void)hipLaunchCooperativeKernel((void*)lstm_loop, dim3(NWG), dim3(NTHR), args,
                                     131072 /* dynamic LDS: weight slice */, stream);
}

// Round 10
// 6380.148 us; speedup vs baseline: 2.8641x; 1.2022x over previous
//
#include <hip/hip_runtime.h>
#include <stdint.h>

// ---------------- constants ----------------
#define NWG   128        // cooperative grid: 1 WG per CU
#define NTHR  512        // 8 waves: (op x,h) x (khalf) x (m row-half)
#define Tsz   512

typedef __attribute__((ext_vector_type(8))) short short8;      // 8 bf16 (4 VGPRs)
typedef __attribute__((ext_vector_type(4))) float f32x4;
typedef __attribute__((ext_vector_type(4))) unsigned uintx4;   // asm-legal 128b vector

__device__ __forceinline__ unsigned short f2bf(float f) {
    unsigned u = __builtin_bit_cast(unsigned, f);
    u += 0x7fffu + ((u >> 16) & 1u);          // RNE
    return (unsigned short)(u >> 16);
}
__device__ __forceinline__ float sigm(float x) {
    float e = __expf(-__builtin_fabsf(x));
    float r = 1.0f / (1.0f + e);
    return x >= 0.0f ? r : 1.0f - r;          // overflow-safe
}
__device__ __forceinline__ float tanh_(float x) {
    float e = __expf(-2.0f * __builtin_fabsf(x));
    float r = (1.0f - e) / (1.0f + e);
    return x >= 0.0f ? r : -r;                // overflow-safe
}

// ---- device-coherent asm primitives (round-3 lesson: waitcnt INSIDE asm
// for loads; stores are hazard-free).  sc0 sc1 = write through to LLC. ----
__device__ __forceinline__ void st16_cc(unsigned short* p, uintx4 v) {
    asm volatile("global_store_dwordx4 %0, %1, off sc0 sc1" :: "v"(p), "v"(v) : "memory");
}
__device__ __forceinline__ void st4_cc(unsigned* p, unsigned v) {
    asm volatile("global_store_dword %0, %1, off sc0 sc1" :: "v"(p), "v"(v) : "memory");
}
__device__ __forceinline__ void drain_vm() {
    asm volatile("s_waitcnt vmcnt(0)" ::: "memory");
}
__device__ __forceinline__ unsigned ld4_cc(const unsigned* p) {
    unsigned v;
    asm volatile("global_load_dword %0, %1, off sc0 sc1\n\t"
                 "s_waitcnt vmcnt(0)"
                 : "=&v"(v) : "v"(p) : "memory");
    return v;
}
// LDS-only WG barrier: NO vmcnt drain (unlike __syncthreads, which emits
// s_waitcnt vmcnt(0) -- guide §5).  Keeps the x-prefetch VMEM loads in
// flight across the barrier.  "memory" clobber pins compiler mem ordering.
__device__ __forceinline__ void bar_lds() {
    asm volatile("s_waitcnt lgkmcnt(0)\n\ts_barrier" ::: "memory");
}

// ---------------- prep kernels ----------------
// x [B][T][D] f32  ->  xb [t][kb(128)][b(64)][8] bf16   (MFMA A-fragment-native)
__global__ void cast_x(const float* __restrict__ x, unsigned short* __restrict__ xb) {
    int o = blockIdx.x * 256 + threadIdx.x;       // 512*128*64 = 4,194,304
    int t = o >> 13;
    int r = o & 8191;
    int kb = r >> 6;
    int b  = r & 63;
    const float* s = x + (((size_t)b * Tsz + t) * 1024 + kb * 8);
    float4 f0 = ((const float4*)s)[0];
    float4 f1 = ((const float4*)s)[1];
    unsigned short tmp[8];
    tmp[0] = f2bf(f0.x); tmp[1] = f2bf(f0.y); tmp[2] = f2bf(f0.z); tmp[3] = f2bf(f0.w);
    tmp[4] = f2bf(f1.x); tmp[5] = f2bf(f1.y); tmp[6] = f2bf(f1.z); tmp[7] = f2bf(f1.w);
    ((uint4*)xb)[o] = *(const uint4*)tmp;
}

// W [2048][4096] f32 -> wc [w(128)][kb(256)][n(32)][8] bf16 in MFMA B-layout, columns permuted
__global__ void build_wc(const float* __restrict__ W0, const float* __restrict__ W1,
                         unsigned short* __restrict__ wc0, unsigned short* __restrict__ wc1) {
    int o = blockIdx.x * 256 + threadIdx.x;       // 2*128*256*32 = 2,097,152
    int layer = o >> 20;
    int r = o & 1048575;
    int w  = r >> 13;
    int r2 = r & 8191;
    int kb = r2 >> 5;
    int n  = r2 & 31;
    int nt = n >> 4, n16 = n & 15;
    int g = n16 >> 2, q = n16 & 3;
    int col = g * 1024 + w * 8 + nt * 4 + q;
    const float* W = layer ? W1 : W0;
    unsigned short* wc = layer ? wc1 : wc0;
    unsigned short tmp[8];
#pragma unroll
    for (int i = 0; i < 8; ++i) tmp[i] = f2bf(W[(size_t)(kb * 8 + i) * 4096 + col]);
    ((uint4*)wc)[r] = *(const uint4*)tmp;
}

// permuted biases pb[layer][w][32] f32 + flag-barrier slots (ws poisoned each launch!)
__global__ void build_pb(const float* __restrict__ b0, const float* __restrict__ b1,
                         float* __restrict__ pb, unsigned* __restrict__ flg) {
    int o = blockIdx.x * 256 + threadIdx.x;       // 8192
    if (o < 2048) flg[o] = 0u;                    // 128 slots x 64B stride
    int layer = o >> 12;
    int r = o & 4095;
    int w = r >> 5;
    int n = r & 31;
    int nt = n >> 4, n16 = n & 15;
    int g = n16 >> 2, q = n16 & 3;
    const float* bb = layer ? b1 : b0;
    pb[o] = bb[g * 1024 + w * 8 + nt * 4 + q];
}

// ---------------- full-fence grid barrier (init + layer boundary ONLY) ----
__device__ __forceinline__ void gbar_full(unsigned* flg, unsigned& bseq, int w, int tid) {
    ++bseq;
    __syncthreads();
    if (tid == 0) { __threadfence(); st4_cc(flg + w * 16, bseq); }   // release: wb L2
    if (tid < 128) {
        while (ld4_cc(flg + tid * 16) < bseq) __builtin_amdgcn_s_sleep(1);
    }
    __syncthreads();
    if (tid == 0) __threadfence();                // acquire: inv L1/L2
    __syncthreads();
}

// ---------------- A-fragment issue / consume ----------------
// issue_a: 32 x 16B loads (compiler loads -> IR-visible, auto-waitcnt'd).
__device__ __forceinline__ void issue_a(const unsigned short* a0p, short8 A0[16], short8 A1[16]) {
#pragma unroll
    for (int s = 0; s < 16; ++s) {
        A0[s] = *(const short8*)(a0p + s * 2048);          // kb += 4 per s
        A1[s] = *(const short8*)(a0p + s * 2048 + 128);    // +16 rows
    }
}
__device__ __forceinline__ void mfma16(const short8 A0[16], const short8 A1[16], const short8* lb,
                                       f32x4& c00, f32x4& c01, f32x4& c10, f32x4& c11) {
#pragma unroll
    for (int s = 0; s < 16; ++s) {
        short8 bf0 = lb[s * 128];        // kb += 4 per s -> +128 16B units
        short8 bf1 = lb[s * 128 + 16];   // +16 cols
        c00 = __builtin_amdgcn_mfma_f32_16x16x32_bf16(A0[s], bf0, c00, 0, 0, 0);
        c01 = __builtin_amdgcn_mfma_f32_16x16x32_bf16(A0[s], bf1, c01, 0, 0, 0);
        c10 = __builtin_amdgcn_mfma_f32_16x16x32_bf16(A1[s], bf0, c10, 0, 0, 0);
        c11 = __builtin_amdgcn_mfma_f32_16x16x32_bf16(A1[s], bf1, c11, 0, 0, 0);
    }
}

// ---------------- persistent LSTM loop ----------------
// ROUND-10: round-9 structure (8 waves, x||h concurrent, LDS weights,
// write-once h-ring, flag barrier) + forced latency hiding:
//  * x-waves: single rotating A buffer; step t issues t+1's loads right
//    after the MFMAs consume them.  In-step barriers are LDS-only (no
//    vmcnt drain) so the prefetch flies under gates+publish+barrier.
//  * h-waves: all 32 loads issued before any MFMA (sched_barrier(0)) ->
//    one latency exposure.  Publish/flag/poll moved to waves 4-5 so their
//    vmcnt(0) drain never touches the x-prefetch.
//  * c-state lives in a REGISTER (cpf) -- removes per-step cst traffic and
//    the same-thread VMEM RAW hazard of dropping the __syncthreads drains.
__launch_bounds__(NTHR, 2)
__global__ void lstm_loop(const unsigned short* __restrict__ xb,
                          unsigned short* __restrict__ y0b,
                          const unsigned short* __restrict__ wc0,
                          const unsigned short* __restrict__ wc1,
                          const float* __restrict__ pb,
                          const int* __restrict__ lens,
                          unsigned short* __restrict__ hring,
                          unsigned* __restrict__ flg,
                          float* __restrict__ out) {
    extern __shared__ short8 lwc[];     // 131072 B: weight slice [kb 0..255][n 32] 16B units
    __shared__ float zbuf[3][64][33];   // [slice][b][col32], +1 pad vs bank conflicts
    __shared__ float pbl[2][32];
    __shared__ __align__(16) unsigned short hsh[64][8];   // h staging -> 64 dwordx4 stores

    const int w = blockIdx.x;
    const int tid = threadIdx.x;
    const int lane = tid & 63;
    const int wave = tid >> 6;        // 0..7
    const int m     = wave & 1;        // row half: rows [m*32, m*32+32)
    const int khalf = (wave >> 1) & 1; // K half within the operand's K=1024
    const int op    = wave >> 2;       // 0 = x operand, 1 = h operand
    const int q16 = lane >> 4;
    const int n16 = lane & 15;

    const int aoff = ((khalf * 64 + q16) * 64 + m * 32 + n16) * 8;       // [kb][b][8]
    const short8* lb = lwc + ((op * 128 + khalf * 64 + q16) * 32 + n16); // kb base in lwc

    // ---- per-launch init (ws is re-poisoned every launch) ----
    if (tid < 256) st4_cc((unsigned*)hring + w * 256 + tid, 0u);  // zero ring slot 0 (bypass)
    if (tid < 64) pbl[tid >> 5][tid & 31] = pb[((tid >> 5) * 128 + w) * 32 + (tid & 31)];
    const int lenb = lens[tid & 63];
    drain_vm();                                                   // slot-0 zeros at LLC
    unsigned bseq = 0;
    gbar_full(flg, bseq, w, tid);

    for (int layer = 0; layer < 2; ++layer) {
        const unsigned short* xsrc = layer ? y0b : xb;
        const unsigned short* wc   = layer ? wc1 : wc0;

        // ---- stage this layer's 128 KB weight slice into LDS (once) ----
        {
            const short8* gsrc = (const short8*)(wc + (size_t)w * 65536);
#pragma unroll 4
            for (int i = 0; i < 16; ++i) lwc[tid + i * 512] = gsrc[tid + i * 512];
        }
        __syncthreads();

        float hpf = 0.f;   // this thread's own h(b, jj): hold-state source
        float cpf = 0.f;   // this thread's own c(b, jj): REGISTER c-state
        const int b  = tid & 63;
        const int jj = wave;
        const int cb = (jj >> 2) * 16 + (jj & 3);

        short8 A0[16], A1[16];
        if (op == 0) issue_a(xsrc + aoff, A0, A1);    // prefetch A_x(t=0)

        for (int t = 0; t < Tsz; ++t) {
            // ---- h-waves: load-then-MFMA with forced full hoist ----
            if (op == 1) {
                issue_a(hring + (size_t)t * 65536 + aoff, A0, A1);
                __builtin_amdgcn_sched_barrier(0);    // all 32 loads issue before MFMAs
            }
            f32x4 c00 = {0.f,0.f,0.f,0.f}, c01 = {0.f,0.f,0.f,0.f};
            f32x4 c10 = {0.f,0.f,0.f,0.f}, c11 = {0.f,0.f,0.f,0.f};
            mfma16(A0, A1, lb, c00, c01, c10, c11);

            // ---- stage 1: zbuf writes (x-k0 -> 0, h-k0 -> 1, h-k1 -> 2) ----
            const int rowb = m * 32 + q16 * 4;
            if (!(op == 0 && khalf == 1)) {
                const int slice = op ? (1 + khalf) : 0;
#pragma unroll
                for (int r = 0; r < 4; ++r) {
                    zbuf[slice][rowb + r][n16]           = c00[r];
                    zbuf[slice][rowb + r][n16 + 16]      = c01[r];
                    zbuf[slice][rowb + 16 + r][n16]      = c10[r];
                    zbuf[slice][rowb + 16 + r][n16 + 16] = c11[r];
                }
            }
            // ---- x-waves: A regs now dead -> issue t+1 prefetch (pinned here
            //      by bar_lds clobbers; flies under gates+publish+barrier) ----
            if (op == 0 && t + 1 < Tsz) issue_a(xsrc + (size_t)(t + 1) * 65536 + aoff, A0, A1);
            bar_lds();
            // ---- stage 2: x-k1 accumulates into slice 0 ----
            if (op == 0 && khalf == 1) {
#pragma unroll
                for (int r = 0; r < 4; ++r) {
                    zbuf[0][rowb + r][n16]           += c00[r];
                    zbuf[0][rowb + r][n16 + 16]      += c01[r];
                    zbuf[0][rowb + 16 + r][n16]      += c10[r];
                    zbuf[0][rowb + 16 + r][n16 + 16] += c11[r];
                }
            }
            bar_lds();

            // ---- gates + state update: 512 threads, one (b, jj) each ----
            const bool active = (t < lenb);
            {
                float zi = zbuf[0][b][cb]      + zbuf[1][b][cb]      + zbuf[2][b][cb]      + pbl[layer][cb];
                float zc = zbuf[0][b][cb + 4]  + zbuf[1][b][cb + 4]  + zbuf[2][b][cb + 4]  + pbl[layer][cb + 4];
                float zf = zbuf[0][b][cb + 8]  + zbuf[1][b][cb + 8]  + zbuf[2][b][cb + 8]  + pbl[layer][cb + 8];
                float zo = zbuf[0][b][cb + 12] + zbuf[1][b][cb + 12] + zbuf[2][b][cb + 12] + pbl[layer][cb + 12];
                if (active) {
                    cpf = cpf * sigm(zf + 1.0f) + sigm(zi) * tanh_(zc);
                    hpf = tanh_(cpf) * sigm(zo);
                }  // inactive: hold hpf/cpf (dynamic_rnn state-hold)
                unsigned short hv = f2bf(hpf);
                hsh[b][jj] = hv;
                const int hi = (w * 64 + b) * 8 + jj;
                if (layer == 0) {
                    y0b[(size_t)t * 65536 + hi] = active ? hv : (unsigned short)0;
                } else {
                    out[(size_t)(b * Tsz + t) * 1024 + w * 8 + jj] = active ? hpf : 0.0f;
                }
            }
            bar_lds();         // hsh visible to wave 4
            ++bseq;
            if (wave == 4) {   // h-wave: publish ring slot t+1; its vmcnt(0) drain
                               // does NOT touch the x-waves' in-flight prefetch
                uintx4 v = ((const uintx4*)hsh)[lane];
                st16_cc((unsigned short*)hring + (size_t)(t + 1) * 65536
                        + (size_t)w * 512 + (size_t)lane * 8, v);
                drain_vm();    // wave-4-only; lane 0 stores the flag after
            }
            if (tid == 256) st4_cc(flg + w * 16, bseq);
            if (tid >= 256 && tid < 384) {   // waves 4-5 poll the 128 slots
                while (ld4_cc(flg + (tid - 256) * 16) < bseq) __builtin_amdgcn_s_sleep(1);
            }
            bar_lds();         // release all waves into step t+1
        }
        // ---- final (h, c) stacks: straight from registers ----
        {
            const int j = w * 8 + jj;
            out[33554432 + layer * 65536 + b * 1024 + j]          = hpf;   // h_stack
            out[33554432 + 131072 + layer * 65536 + b * 1024 + j] = cpf;   // c_stack
        }
        if (layer == 0) {
            // re-zero ring slot 0 for layer 1 (bypass, drained); full-fence barrier
            // publishes cached y0b AND invalidates layer-0 ring cached lines.
            if (tid < 256) st4_cc((unsigned*)hring + w * 256 + tid, 0u);
            drain_vm();
            gbar_full(flg, bseq, w, tid);
        }
    }
}

// ---------------- launcher ----------------
extern "C" void kernel_launch(void* const* d_in, const int* in_sizes, int n_in,
                              void* d_out, int out_size, void* d_ws, size_t ws_size,
                              hipStream_t stream) {
    const float* x    = (const float*)d_in[0];
    const int*   lens = (const int*)d_in[1];     // integer inputs arrive as int32
    const float* W0   = (const float*)d_in[2];
    const float* b0   = (const float*)d_in[3];
    const float* W1   = (const float*)d_in[4];
    const float* b1   = (const float*)d_in[5];
    char* ws = (char*)d_ws;

    unsigned short* xb   = (unsigned short*)(ws);                    //  67,108,864 B
    unsigned short* y0b  = (unsigned short*)(ws + 67108864);         //  67,108,864 B
    unsigned short* wc0  = (unsigned short*)(ws + 134217728);        //  16,777,216 B
    unsigned short* wc1  = (unsigned short*)(ws + 150994944);        //  16,777,216 B
    float*          pb   = (float*)         (ws + 167772160);        //      32,768 B
    unsigned*       flg  = (unsigned*)      (ws + 168329216);        //       8,192 B
    unsigned short* hrng = (unsigned short*)(ws + 168337408);        //  67,239,936 B (513 slots)
                                                                     //  total 235,577,344 B (proven)

    hipLaunchKernelGGL(cast_x,   dim3(16384), dim3(256), 0, stream, x, xb);
    hipLaunchKernelGGL(build_wc, dim3(8192),  dim3(256), 0, stream, W0, W1, wc0, wc1);
    hipLaunchKernelGGL(build_pb, dim3(32),    dim3(256), 0, stream, b0, b1, pb, flg);

    float* out = (float*)d_out;
    void* args[] = { &xb, &y0b, &wc0, &wc1, &pb, &lens, &hrng, &flg, &out };
    (void)hipLaunchCooperativeKernel((void*)lstm_loop, dim3(NWG), dim3(NTHR), args,
                                     131072 /* dynamic LDS: weight slice */, stream);
}